// Round 1
// baseline (192.662 us; speedup 1.0000x reference)
//
#include <hip/hip_runtime.h>

// PatchesCreate: images [B=64, H=384, W=384, C=3] f32 (NHWC) ->
// patches [B, G*G=576, P*P*C=768] f32, P=16, G=24.
//
// out[b][gy*G+gx][py*P*C + px*C + c] = in[b][gy*P+py][gx*P+px][c]
//
// Innermost 48 floats (one patch row, P*C) are contiguous in BOTH input and
// output -> move data as float4 (12 vectors per patch row). Threads indexed
// in OUTPUT order: stores fully coalesced; loads are 192 B contiguous
// segments (3 full cache lines) at 1152 B stride -> no wasted fetch.

constexpr int Bsz = 64;
constexpr int Hh  = 384;
constexpr int Ww  = 384;
constexpr int C   = 3;
constexpr int P   = 16;
constexpr int G   = 24;                    // 384/16
constexpr int ROW4   = Ww * C / 4;         // 288 float4 per image row
constexpr int CHUNK4 = P * C / 4;          // 12 float4 per patch row
constexpr int TOT4   = Bsz * G * G * P * CHUNK4;  // 7,077,888 float4 total

__global__ __launch_bounds__(256)
void patches_kernel(const float4* __restrict__ in, float4* __restrict__ out) {
    int tid = blockIdx.x * blockDim.x + threadIdx.x;
    if (tid >= TOT4) return;

    // Decompose tid as output-order index: [b][gy][gx][py][k], k in [0,12)
    int k  = tid % CHUNK4;
    int t  = tid / CHUNK4;
    int py = t % P;   t /= P;
    int gx = t % G;   t /= G;
    int gy = t % G;
    int b  = t / G;

    int row  = b * Hh + gy * P + py;       // source image row
    int iidx = row * ROW4 + gx * CHUNK4 + k;

    out[tid] = in[iidx];
}

extern "C" void kernel_launch(void* const* d_in, const int* in_sizes, int n_in,
                              void* d_out, int out_size, void* d_ws, size_t ws_size,
                              hipStream_t stream) {
    const float4* in  = (const float4*)d_in[0];
    float4*       out = (float4*)d_out;

    constexpr int BLOCK = 256;
    constexpr int GRID  = (TOT4 + BLOCK - 1) / BLOCK;  // 27,648 blocks
    patches_kernel<<<GRID, BLOCK, 0, stream>>>(in, out);
}

// Round 3
// 192.135 us; speedup vs baseline: 1.0027x; 1.0027x over previous
//
#include <hip/hip_runtime.h>

// PatchesCreate: images [B=64, H=384, W=384, C=3] f32 (NHWC) ->
// patches [B, G*G=576, P*P*C=768] f32, P=16, G=24.
//
// out[b][gy*G+gx][py*P*C + px*C + c] = in[b][gy*P+py][gx*P+px][c]
//
// Threads indexed in OUTPUT float4 order: stores fully coalesced (1 KiB/wave);
// reads are 192 B contiguous segments (3 full 64 B lines) at 1152 B stride ->
// every fetched line fully consumed. 4 float4 per thread via stride = total
// thread count, so each load/store instruction remains lane-contiguous.
// Nontemporal hints: pure streaming, zero reuse -> skip cache allocation.
// NOTE: nontemporal builtins need a NATIVE clang vector type, not
// HIP_vector_type -> use ext_vector_type(4) float.

typedef float f4 __attribute__((ext_vector_type(4)));

constexpr int Bsz = 64;
constexpr int Hh  = 384;
constexpr int Ww  = 384;
constexpr int C   = 3;
constexpr int P   = 16;
constexpr int G   = 24;                       // 384/16
constexpr int ROW4   = Ww * C / 4;            // 288 float4 per image row
constexpr int CHUNK4 = P * C / 4;             // 12 float4 per patch row
constexpr int TOT4   = Bsz * G * G * P * CHUNK4;  // 7,077,888 float4 total
constexpr int ELEMS  = 4;                     // float4 moved per thread
constexpr int NTHREADS = TOT4 / ELEMS;        // 1,769,472 (exact)

__global__ __launch_bounds__(256)
void patches_kernel(const f4* __restrict__ in, f4* __restrict__ out) {
    int tid = blockIdx.x * blockDim.x + threadIdx.x;

#pragma unroll
    for (int e = 0; e < ELEMS; ++e) {
        int idx = tid + e * NTHREADS;         // output-order float4 index

        // Decompose idx: [b][gy][gx][py][k], k in [0,12)
        int k  = idx % CHUNK4;
        int t  = idx / CHUNK4;
        int py = t % P;   t /= P;
        int gx = t % G;   t /= G;
        int gy = t % G;
        int b  = t / G;

        int row  = b * Hh + gy * P + py;      // source image row
        int iidx = row * ROW4 + gx * CHUNK4 + k;

        f4 v = __builtin_nontemporal_load(in + iidx);
        __builtin_nontemporal_store(v, out + idx);
    }
}

extern "C" void kernel_launch(void* const* d_in, const int* in_sizes, int n_in,
                              void* d_out, int out_size, void* d_ws, size_t ws_size,
                              hipStream_t stream) {
    const f4* in  = (const f4*)d_in[0];
    f4*       out = (f4*)d_out;

    constexpr int BLOCK = 256;
    constexpr int GRID  = NTHREADS / BLOCK;   // 6,912 blocks
    patches_kernel<<<GRID, BLOCK, 0, stream>>>(in, out);
}